// Round 1
// baseline (2052.802 us; speedup 1.0000x reference)
//
#include <hip/hip_runtime.h>
#include <hip/hip_bf16.h>

#define S_DIM 2048
#define DV_DIM 64
#define NEGV (-1000000000.0f)

typedef __bf16 bf16x8 __attribute__((ext_vector_type(8)));
typedef __bf16 bf16x4 __attribute__((ext_vector_type(4)));
typedef float  f32x4  __attribute__((ext_vector_type(4)));
typedef unsigned short u16;
typedef u16 u16x8 __attribute__((ext_vector_type(8)));

#define MFMA(a, b, c) __builtin_amdgcn_mfma_f32_16x16x32_bf16(a, b, c, 0, 0, 0)

// ---------------------------------------------------------------------------
// Pre-pass 1: a2 [bh][64 f][2048 t] f32  ->  a2hi/a2lo [bh][2048 t][64 f] bf16
// (one-time transpose + hi/lo split; main kernel was doing this 128x per bh)
// ---------------------------------------------------------------------------
__global__ __launch_bounds__(256)
void pack_a2_kernel(const float* __restrict__ a2,
                    u16* __restrict__ hi, u16* __restrict__ lo)
{
    const int bh = blockIdx.x >> 5;
    const int tb = (blockIdx.x & 31) << 6;          // 64-col tile of t
    __shared__ u16 sh[64][65];
    __shared__ u16 sl[64][65];
    const float* src = a2 + (size_t)bh * 64 * S_DIM + tb;
    const int tid = threadIdx.x;
#pragma unroll
    for (int i = 0; i < 16; ++i) {
        int e = tid + i * 256;
        int f = e >> 6, c = e & 63;                 // coalesced along t
        float v = src[(size_t)f * S_DIM + c];
        __bf16 h = (__bf16)v;
        __bf16 l = (__bf16)(v - (float)h);
        union { __bf16 b; u16 u; } ch_, cl_;
        ch_.b = h; cl_.b = l;
        sh[c][f] = ch_.u;                           // store transposed
        sl[c][f] = cl_.u;
    }
    __syncthreads();
    const int r = tid >> 2, k0 = (tid & 3) << 4;    // 4 threads/row, 16 k each
    u16x8 h0, h1, l0, l1;
#pragma unroll
    for (int j = 0; j < 8; ++j) {
        h0[j] = sh[r][k0 + j]; h1[j] = sh[r][k0 + 8 + j];
        l0[j] = sl[r][k0 + j]; l1[j] = sl[r][k0 + 8 + j];
    }
    size_t off = ((size_t)bh * S_DIM + tb + r) * 64 + k0;
    *(u16x8*)(hi + off) = h0; *(u16x8*)(hi + off + 8) = h1;
    *(u16x8*)(lo + off) = l0; *(u16x8*)(lo + off + 8) = l1;
}

// ---------------------------------------------------------------------------
// Pre-pass 2: v [bh][2048 t][64 d] f32 -> vT [bh][64 d][2048 t] bf16
// ---------------------------------------------------------------------------
__global__ __launch_bounds__(256)
void pack_v_kernel(const float* __restrict__ v, u16* __restrict__ vT)
{
    const int bh = blockIdx.x >> 5;
    const int tb = (blockIdx.x & 31) << 6;
    __shared__ u16 sv[64][65];
    const int tid = threadIdx.x;
#pragma unroll
    for (int i = 0; i < 16; ++i) {
        int e = tid + i * 256;
        int t = e >> 6, d = e & 63;                 // coalesced along d
        float x = v[((size_t)bh * S_DIM + tb + t) * 64 + d];
        union { __bf16 b; u16 u; } cv_;
        cv_.b = (__bf16)x;
        sv[d][t] = cv_.u;
    }
    __syncthreads();
    const int r = tid >> 2, c0 = (tid & 3) << 4;
    u16x8 t0v, t1v;
#pragma unroll
    for (int j = 0; j < 8; ++j) { t0v[j] = sv[r][c0 + j]; t1v[j] = sv[r][c0 + 8 + j]; }
    size_t off = ((size_t)bh * 64 + r) * S_DIM + tb + c0;
    *(u16x8*)(vT + off) = t0v; *(u16x8*)(vT + off + 8) = t1v;
}

// ---------------------------------------------------------------------------
// Pre-pass 3: mask int32 -> bitmask [b*2048 rows][64 uint words]  (134MB->4.2MB)
// ---------------------------------------------------------------------------
__global__ __launch_bounds__(256)
void pack_mask_kernel(const int* __restrict__ mask, unsigned int* __restrict__ mbits)
{
    const int row = blockIdx.x;                     // b*2048 + s, 16384 rows
    const int tid = threadIdx.x;
    const int wv = tid >> 6, lane = tid & 63;
    const int* mp = mask + (size_t)row * S_DIM;
#pragma unroll
    for (int it = 0; it < 8; ++it) {
        int c = it * 256 + wv * 64 + lane;          // coalesced
        unsigned long long b = __ballot(mp[c] != 0);
        if (lane == 0) {
            mbits[(size_t)row * 64 + it * 8 + wv * 2]     = (unsigned int)b;
            mbits[(size_t)row * 64 + it * 8 + wv * 2 + 1] = (unsigned int)(b >> 32);
        }
    }
}

// ---------------------------------------------------------------------------
// Main kernel. Computes S^T tiles: MFMA(A=a2pack, B=a1) so that
//   acc[ct][rr] = S[row0+ln][cbase + ct*16 + q*4 + rr]
// -> per-lane scalar softmax (row = ln), float4 NT attn stores, uint4 mask.
// ---------------------------------------------------------------------------
__global__ __launch_bounds__(512, 2)
void fra_main(const u16* __restrict__ a2hi, const u16* __restrict__ a2lo,
              const u16* __restrict__ vT, const unsigned int* __restrict__ mbits,
              const float* __restrict__ a1,
              float* __restrict__ out, float* __restrict__ attn)
{
    const int tid  = threadIdx.x;
    const int wv   = tid >> 6;
    const int lane = tid & 63;
    const int q    = lane >> 4;
    const int ln   = lane & 15;

    // XCD-grouped swizzle: each XCD owns 8 consecutive bh entirely ->
    // a2pack[bh] (512KB) + vT[bh] (256KB) stay resident in the 4MB XCD L2.
    const int idx  = blockIdx.x;
    const int w    = (idx & 7) * 1024 + (idx >> 3);
    const int bh   = w >> 7;
    const int row0 = (w & 127) << 4;

    __shared__ float redmax[8][16];
    __shared__ float redsum[8][16];
    // wave-private: 16 rows (s) x 128 cols (t) bf16, stride 136 (=272B rows).
    // No barriers needed around its use. Reused as fp32 out staging at the end.
    __shared__ __align__(16) __bf16 pbuf[8][16][136];

    const int cbase = wv * 256;

    // ---- a1 fragments (B operand now), hi/lo split ----
    const float* a1p = a1 + ((size_t)bh * S_DIM + row0 + ln) * 64 + q * 8;
    bf16x8 a1hi[2], a1lo[2];
#pragma unroll
    for (int kb = 0; kb < 2; ++kb) {
        const float4 f0 = *(const float4*)(a1p + kb * 32);
        const float4 f1 = *(const float4*)(a1p + kb * 32 + 4);
        float tf[8] = {f0.x, f0.y, f0.z, f0.w, f1.x, f1.y, f1.z, f1.w};
#pragma unroll
        for (int j = 0; j < 8; ++j) {
            __bf16 h = (__bf16)tf[j];
            __bf16 l = (__bf16)(tf[j] - (float)h);
            a1hi[kb][j] = h;
            a1lo[kb][j] = l;
        }
    }

    // ---- scores S^T: A-frags are contiguous 16B loads from packed a2 ----
    f32x4 acc[16];
#pragma unroll
    for (int ct = 0; ct < 16; ++ct) acc[ct] = f32x4{0.f, 0.f, 0.f, 0.f};

    const u16* ah = a2hi + ((size_t)bh * S_DIM + cbase + ln) * 64 + q * 8;
    const u16* al = a2lo + ((size_t)bh * S_DIM + cbase + ln) * 64 + q * 8;

#pragma unroll
    for (int ct = 0; ct < 16; ++ct) {
        const size_t o = (size_t)ct * 1024;         // 16 rows * 64 k
        bf16x8 h0 = *(const bf16x8*)(ah + o);
        bf16x8 h1 = *(const bf16x8*)(ah + o + 32);
        bf16x8 l0 = *(const bf16x8*)(al + o);
        bf16x8 l1 = *(const bf16x8*)(al + o + 32);
        acc[ct] = MFMA(h0, a1hi[0], acc[ct]);
        acc[ct] = MFMA(h1, a1hi[1], acc[ct]);
        acc[ct] = MFMA(l0, a1hi[0], acc[ct]);
        acc[ct] = MFMA(l1, a1hi[1], acc[ct]);
        acc[ct] = MFMA(h0, a1lo[0], acc[ct]);
        acc[ct] = MFMA(h1, a1lo[1], acc[ct]);
    }

    // ---- mask via bit-words: lane needs bits t = cbase + ct*16 + q*4 + rr,
    //      word = ct>>1, bit = (ct&1)*16 + q*4 + rr. 2 x uint4 loads. ----
    const unsigned int* mbp = mbits + ((size_t)(bh >> 3) * S_DIM + row0 + ln) * 64 + wv * 8;
    const uint4 mwa = *(const uint4*)mbp;
    const uint4 mwb = *(const uint4*)(mbp + 4);
    const unsigned int mw[8] = {mwa.x, mwa.y, mwa.z, mwa.w, mwb.x, mwb.y, mwb.z, mwb.w};

    float lm[4] = {NEGV, NEGV, NEGV, NEGV};
#pragma unroll
    for (int ct = 0; ct < 16; ++ct) {
        const unsigned int nib = mw[ct >> 1] >> (((ct & 1) << 4) + (q << 2));
#pragma unroll
        for (int rr = 0; rr < 4; ++rr) {
            float s = ((nib >> rr) & 1u) ? acc[ct][rr] : NEGV;
            acc[ct][rr] = s;
            lm[rr] = fmaxf(lm[rr], s);
        }
    }
    // row = ln is fixed per lane: scalar max, 2 shuffles combine the q-groups.
    float m0 = fmaxf(fmaxf(lm[0], lm[1]), fmaxf(lm[2], lm[3]));
    m0 = fmaxf(m0, __shfl_xor(m0, 16, 64));
    m0 = fmaxf(m0, __shfl_xor(m0, 32, 64));
    if (lane < 16) redmax[wv][lane] = m0;
    __syncthreads();
    float rmax = redmax[0][ln];
#pragma unroll
    for (int w8 = 1; w8 < 8; ++w8) rmax = fmaxf(rmax, redmax[w8][ln]);

    // ---- exp + row sum ----
    float ls[4] = {0.f, 0.f, 0.f, 0.f};
#pragma unroll
    for (int ct = 0; ct < 16; ++ct) {
#pragma unroll
        for (int rr = 0; rr < 4; ++rr) {
            float p = __expf(acc[ct][rr] - rmax);
            acc[ct][rr] = p;
            ls[rr] += p;
        }
    }
    float s0 = (ls[0] + ls[1]) + (ls[2] + ls[3]);
    s0 += __shfl_xor(s0, 16, 64);
    s0 += __shfl_xor(s0, 32, 64);
    if (lane < 16) redsum[wv][lane] = s0;
    __syncthreads();
    float rs = redsum[0][ln];
#pragma unroll
    for (int w8 = 1; w8 < 8; ++w8) rs += redsum[w8][ln];
    const float rinv = 1.0f / rs;

    // ---- normalize + attn store (float4 NT) + PV; pbuf is wave-private so
    //      no barriers in this loop. ----
    float* attnp = attn + ((size_t)bh * S_DIM + row0 + ln) * S_DIM + cbase + (q << 2);
    const u16* vp = vT + ((size_t)bh * 64 + ln) * S_DIM + cbase + q * 8;

    f32x4 oacc[4];
#pragma unroll
    for (int nt = 0; nt < 4; ++nt) oacc[nt] = f32x4{0.f, 0.f, 0.f, 0.f};

#pragma unroll
    for (int ch = 0; ch < 2; ++ch) {
#pragma unroll
        for (int t8 = 0; t8 < 8; ++t8) {
            const int ct = ch * 8 + t8;
            f32x4 p;
            bf16x4 pk;
#pragma unroll
            for (int rr = 0; rr < 4; ++rr) {
                float a = acc[ct][rr] * rinv;
                p[rr]  = a;
                pk[rr] = (__bf16)a;
            }
            __builtin_nontemporal_store(p, (f32x4*)(attnp + ct * 16));
            *(bf16x4*)&pbuf[wv][ln][t8 * 16 + (q << 2)] = pk;   // 8B ds_write
        }
#pragma unroll
        for (int kc = 0; kc < 4; ++kc) {
            bf16x8 af = *(const bf16x8*)&pbuf[wv][ln][kc * 32 + q * 8];
#pragma unroll
            for (int nt = 0; nt < 4; ++nt) {
                bf16x8 bfv = *(const bf16x8*)(vp + (size_t)nt * 16 * S_DIM + ch * 128 + kc * 32);
                oacc[nt] = MFMA(af, bfv, oacc[nt]);
            }
        }
    }

    // ---- cross-wave out reduction via LDS (reuse pbuf as fp32, stride 68) ----
    float* ob = (float*)&pbuf[wv][0][0];
#pragma unroll
    for (int nt = 0; nt < 4; ++nt) {
#pragma unroll
        for (int rr = 0; rr < 4; ++rr)
            ob[(q * 4 + rr) * 68 + nt * 16 + ln] = oacc[nt][rr];
    }
    __syncthreads();

#pragma unroll
    for (int i = 0; i < 2; ++i) {
        int e = tid + i * 512;
        int r = e >> 6, c = e & 63;
        float s = 0.f;
#pragma unroll
        for (int w8 = 0; w8 < 8; ++w8)
            s += ((const float*)&pbuf[w8][0][0])[r * 68 + c];
        out[((size_t)bh * S_DIM + row0 + r) * DV_DIM + c] = s;
    }
}

// ---------------------------------------------------------------------------
// Fallback: previous verified kernel (used only if ws_size is insufficient).
// ---------------------------------------------------------------------------
__global__ __launch_bounds__(512, 2)
void fra_kernel_fb(const float* __restrict__ vptr,
                   const int*   __restrict__ mask,
                   const float* __restrict__ a1,
                   const float* __restrict__ a2,
                   float* __restrict__ out,
                   float* __restrict__ attn)
{
    const int tid  = threadIdx.x;
    const int wv   = tid >> 6;
    const int lane = tid & 63;
    const int q    = lane >> 4;
    const int ln   = lane & 15;

    const int idx  = blockIdx.x;
    const int w    = (idx & 7) * 1024 + (idx >> 3);
    const int bh   = w >> 7;
    const int row0 = (w & 127) << 4;

    __shared__ float redmax[8][16];
    __shared__ float redsum[8][16];
    __shared__ __align__(16) __bf16 pbuf[8][16][136];

    const float* a1p = a1 + ((size_t)bh * S_DIM + row0 + ln) * 64 + q * 8;
    bf16x8 a1hi[2], a1lo[2];
#pragma unroll
    for (int kb = 0; kb < 2; ++kb) {
        const float4 f0 = *(const float4*)(a1p + kb * 32);
        const float4 f1 = *(const float4*)(a1p + kb * 32 + 4);
        float tf[8] = {f0.x, f0.y, f0.z, f0.w, f1.x, f1.y, f1.z, f1.w};
#pragma unroll
        for (int j = 0; j < 8; ++j) {
            __bf16 h = (__bf16)tf[j];
            __bf16 l = (__bf16)(tf[j] - (float)h);
            a1hi[kb][j] = h;
            a1lo[kb][j] = l;
        }
    }

    f32x4 acc[16];
#pragma unroll
    for (int ct = 0; ct < 16; ++ct) acc[ct] = f32x4{0.f, 0.f, 0.f, 0.f};

    const int cbase = wv * 256;
    const float* a2p = a2 + (size_t)bh * 64 * S_DIM + (size_t)(q * 8) * S_DIM + ln;

#pragma unroll
    for (int ct = 0; ct < 16; ++ct) {
        const int c0 = cbase + ct * 16;
        bf16x8 bhi[2], blo[2];
#pragma unroll
        for (int kb = 0; kb < 2; ++kb) {
#pragma unroll
            for (int j = 0; j < 8; ++j) {
                float fv = a2p[(size_t)(kb * 32 + j) * S_DIM + c0];
                __bf16 h = (__bf16)fv;
                __bf16 l = (__bf16)(fv - (float)h);
                bhi[kb][j] = h;
                blo[kb][j] = l;
            }
        }
        acc[ct] = MFMA(a1hi[0], bhi[0], acc[ct]);
        acc[ct] = MFMA(a1hi[1], bhi[1], acc[ct]);
        acc[ct] = MFMA(a1lo[0], bhi[0], acc[ct]);
        acc[ct] = MFMA(a1lo[1], bhi[1], acc[ct]);
        acc[ct] = MFMA(a1hi[0], blo[0], acc[ct]);
        acc[ct] = MFMA(a1hi[1], blo[1], acc[ct]);
    }

    const int* mp = mask + ((size_t)(bh >> 3) * S_DIM + row0 + q * 4) * S_DIM + cbase + ln;
    float lmax[4] = {NEGV, NEGV, NEGV, NEGV};
#pragma unroll
    for (int ct = 0; ct < 16; ++ct) {
#pragma unroll
        for (int rr = 0; rr < 4; ++rr) {
            int mv = mp[(size_t)rr * S_DIM + ct * 16];
            float s = mv ? acc[ct][rr] : NEGV;
            acc[ct][rr] = s;
            lmax[rr] = fmaxf(lmax[rr], s);
        }
    }
#pragma unroll
    for (int off = 8; off >= 1; off >>= 1) {
#pragma unroll
        for (int rr = 0; rr < 4; ++rr)
            lmax[rr] = fmaxf(lmax[rr], __shfl_xor(lmax[rr], off, 64));
    }
    if (ln == 0) {
#pragma unroll
        for (int rr = 0; rr < 4; ++rr) redmax[wv][q * 4 + rr] = lmax[rr];
    }
    __syncthreads();
    float rmax[4];
#pragma unroll
    for (int rr = 0; rr < 4; ++rr) {
        float m = redmax[0][q * 4 + rr];
#pragma unroll
        for (int w8 = 1; w8 < 8; ++w8) m = fmaxf(m, redmax[w8][q * 4 + rr]);
        rmax[rr] = m;
    }

    float lsum[4] = {0.f, 0.f, 0.f, 0.f};
#pragma unroll
    for (int ct = 0; ct < 16; ++ct) {
#pragma unroll
        for (int rr = 0; rr < 4; ++rr) {
            float p = __expf(acc[ct][rr] - rmax[rr]);
            acc[ct][rr] = p;
            lsum[rr] += p;
        }
    }
#pragma unroll
    for (int off = 8; off >= 1; off >>= 1) {
#pragma unroll
        for (int rr = 0; rr < 4; ++rr)
            lsum[rr] += __shfl_xor(lsum[rr], off, 64);
    }
    if (ln == 0) {
#pragma unroll
        for (int rr = 0; rr < 4; ++rr) redsum[wv][q * 4 + rr] = lsum[rr];
    }
    __syncthreads();
    float rinv[4];
#pragma unroll
    for (int rr = 0; rr < 4; ++rr) {
        float s2 = redsum[0][q * 4 + rr];
#pragma unroll
        for (int w8 = 1; w8 < 8; ++w8) s2 += redsum[w8][q * 4 + rr];
        rinv[rr] = 1.0f / s2;
    }

    float* attnp = attn + ((size_t)bh * S_DIM + row0 + q * 4) * S_DIM + cbase + ln;
    const float* vp = vptr + (size_t)bh * S_DIM * DV_DIM + (size_t)(cbase + q * 8) * DV_DIM + ln;

    f32x4 oacc[4];
#pragma unroll
    for (int nt = 0; nt < 4; ++nt) oacc[nt] = f32x4{0.f, 0.f, 0.f, 0.f};

#pragma unroll
    for (int ch = 0; ch < 2; ++ch) {
#pragma unroll
        for (int t8 = 0; t8 < 8; ++t8) {
            const int ct = ch * 8 + t8;
#pragma unroll
            for (int rr = 0; rr < 4; ++rr) {
                float a = acc[ct][rr] * rinv[rr];
                attnp[(size_t)rr * S_DIM + ct * 16] = a;
                pbuf[wv][q * 4 + rr][t8 * 16 + ln] = (__bf16)a;
            }
        }
        __syncthreads();
#pragma unroll
        for (int kc = 0; kc < 4; ++kc) {
            bf16x8 af = *(const bf16x8*)&pbuf[wv][ln][kc * 32 + q * 8];
#pragma unroll
            for (int nt = 0; nt < 4; ++nt) {
                bf16x8 bf;
#pragma unroll
                for (int j = 0; j < 8; ++j)
                    bf[j] = (__bf16)vp[(size_t)(ch * 128 + kc * 32 + j) * DV_DIM + nt * 16];
                oacc[nt] = MFMA(af, bf, oacc[nt]);
            }
        }
        __syncthreads();
    }

    float* ob = (float*)&pbuf[wv][0][0];
#pragma unroll
    for (int nt = 0; nt < 4; ++nt) {
#pragma unroll
        for (int rr = 0; rr < 4; ++rr)
            ob[(q * 4 + rr) * 68 + nt * 16 + ln] = oacc[nt][rr];
    }
    __syncthreads();

#pragma unroll
    for (int i = 0; i < 2; ++i) {
        int e = tid + i * 512;
        int r = e >> 6, c = e & 63;
        float s = 0.f;
#pragma unroll
        for (int w8 = 0; w8 < 8; ++w8)
            s += ((const float*)&pbuf[w8][0][0])[r * 68 + c];
        out[((size_t)bh * S_DIM + row0 + r) * DV_DIM + c] = s;
    }
}

extern "C" void kernel_launch(void* const* d_in, const int* in_sizes, int n_in,
                              void* d_out, int out_size, void* d_ws, size_t ws_size,
                              hipStream_t stream) {
    const float* v    = (const float*)d_in[0];
    const int*   mask = (const int*)d_in[1];
    const float* a1   = (const float*)d_in[2];
    const float* a2   = (const float*)d_in[3];
    // d_in[4] = len_q (== S, constant) — unused.

    float* out  = (float*)d_out;
    float* attn = out + (size_t)8 * 8 * 2048 * 64;  // out is 8.39M floats, attn follows

    const size_t n_a2 = (size_t)64 * 2048 * 64;     // elems in a2 / vT
    const size_t need = n_a2 * 3 * sizeof(u16) + (size_t)8 * 2048 * 64 * sizeof(unsigned int);

    if (ws_size >= need) {
        u16* a2hi = (u16*)d_ws;
        u16* a2lo = a2hi + n_a2;
        u16* vTp  = a2lo + n_a2;
        unsigned int* mb = (unsigned int*)(vTp + n_a2);
        pack_a2_kernel<<<2048, 256, 0, stream>>>(a2, a2hi, a2lo);
        pack_v_kernel<<<2048, 256, 0, stream>>>(v, vTp);
        pack_mask_kernel<<<16384, 256, 0, stream>>>(mask, mb);
        fra_main<<<8192, 512, 0, stream>>>(a2hi, a2lo, vTp, mb, a1, out, attn);
    } else {
        fra_kernel_fb<<<8192, 512, 0, stream>>>(v, mask, a1, a2, out, attn);
    }
}